// Round 1
// baseline (544.822 us; speedup 1.0000x reference)
//
#include <hip/hip_runtime.h>

// SGNS scoring: out[b] = dot(W[vii[b,0]], W[vii[b,1]]) over 128 fp32 dims.
// W: fp32 [1e6 x 128] (rows = 512 B), vii: int64 or int32 [16384 x 2]
// (width auto-detected), out: fp32 [16384].
// Latency-bound random gather. This version: 2 samples per 16-lane group
// -> 8 independent 16B row loads per thread (2x the MLP of the previous
// version), one width-detection + index batch amortized over 2 samples.
// Grid: 512 blocks x 256 threads = 2048 waves (8/CU), 8 vmem insts in
// flight per wave -> same 64 in-flight insts/CU but deeper per-wave
// overlap and half the serial detect->index->row chains.

#define BATCH 16384
#define NB_DIMS 128
#define LPS 16                      // lanes per sample-group
#define BLOCK 256
#define GROUPS (BLOCK / LPS)        // 16 groups per block
#define SPT 2                       // samples per group
#define SPB (GROUPS * SPT)          // 32 samples per block

__global__ __launch_bounds__(BLOCK) void sgns_dot_kernel(
    const int* __restrict__ vii32,  // raw words of the index array
    const float* __restrict__ W,
    float* __restrict__ out) {
    const int tid  = threadIdx.x;
    const int lane = tid & (LPS - 1);
    const int g    = tid >> 4;
    const int sA   = blockIdx.x * SPB + g;          // sample A
    const int sB   = sA + GROUPS;                   // sample B (same block)

    // Index-width detection: int64 indices (< 2^20) have all-zero odd
    // int32 words. Check 4 of them -> false-positive prob ~1e-24.
    // Wave-uniform condition => scalar branch, no divergence, and we never
    // touch bytes beyond the actual buffer in either case.
    const bool idx64 = ((vii32[1] | vii32[3] | vii32[5] | vii32[7]) == 0);
    int a0, a1, b0, b1;
    if (idx64) {
        a0 = vii32[4 * sA];     a1 = vii32[4 * sA + 2];
        b0 = vii32[4 * sB];     b1 = vii32[4 * sB + 2];
    } else {
        a0 = vii32[2 * sA];     a1 = vii32[2 * sA + 1];
        b0 = vii32[2 * sB];     b1 = vii32[2 * sB + 1];
    }

    const float4* rA0 = (const float4*)(W + (size_t)a0 * NB_DIMS);
    const float4* rA1 = (const float4*)(W + (size_t)a1 * NB_DIMS);
    const float4* rB0 = (const float4*)(W + (size_t)b0 * NB_DIMS);
    const float4* rB1 = (const float4*)(W + (size_t)b1 * NB_DIMS);

    // 8 independent 16B loads issued back-to-back (deep MLP). Each
    // 16-lane group covers 256 B contiguous per request -> 2 full
    // 128B lines, perfectly coalesced.
    const float4 xA0 = rA0[lane];
    const float4 xA1 = rA1[lane];
    const float4 xB0 = rB0[lane];
    const float4 xB1 = rB1[lane];
    const float4 yA0 = rA0[lane + LPS];
    const float4 yA1 = rA1[lane + LPS];
    const float4 yB0 = rB0[lane + LPS];
    const float4 yB1 = rB1[lane + LPS];

    float accA = 0.0f;
    accA = fmaf(xA0.x, xA1.x, accA);
    accA = fmaf(xA0.y, xA1.y, accA);
    accA = fmaf(xA0.z, xA1.z, accA);
    accA = fmaf(xA0.w, xA1.w, accA);
    accA = fmaf(yA0.x, yA1.x, accA);
    accA = fmaf(yA0.y, yA1.y, accA);
    accA = fmaf(yA0.z, yA1.z, accA);
    accA = fmaf(yA0.w, yA1.w, accA);

    float accB = 0.0f;
    accB = fmaf(xB0.x, xB1.x, accB);
    accB = fmaf(xB0.y, xB1.y, accB);
    accB = fmaf(xB0.z, xB1.z, accB);
    accB = fmaf(xB0.w, xB1.w, accB);
    accB = fmaf(yB0.x, yB1.x, accB);
    accB = fmaf(yB0.y, yB1.y, accB);
    accB = fmaf(yB0.z, yB1.z, accB);
    accB = fmaf(yB0.w, yB1.w, accB);

    // Butterfly reduce both samples across the 16-lane group (groups are
    // 16-aligned, so xor offsets < 16 stay inside the group).
#pragma unroll
    for (int off = 8; off >= 1; off >>= 1) {
        accA += __shfl_xor(accA, off, 64);
        accB += __shfl_xor(accB, off, 64);
    }

    if (lane == 0) {
        out[sA] = accA;
        out[sB] = accB;
    }
}

extern "C" void kernel_launch(void* const* d_in, const int* in_sizes, int n_in,
                              void* d_out, int out_size, void* d_ws, size_t ws_size,
                              hipStream_t stream) {
    const int* vii = (const int*)d_in[0];
    const float* W = (const float*)d_in[1];
    float* out = (float*)d_out;

    dim3 grid(BATCH / SPB);   // 512 blocks
    dim3 block(BLOCK);        // 256 threads = 32 samples/block
    sgns_dot_kernel<<<grid, block, 0, stream>>>(vii, W, out);
}